// Round 4
// baseline (1714.945 us; speedup 1.0000x reference)
//
#include <hip/hip_runtime.h>
#include <hip/hip_bf16.h>

// ---------------------------------------------------------------------------
// AJ-RNN forward: 2-layer LSTM (B=128,T=256,D=64,H=512) with missing-value
// imputation. Round 7: persistent kernel, split-K waves + flag-array barrier.
//  - R6 post-mortem: 4 waves re-read identical A-fragments (264 b128/step) and
//    32-block fetch_add on ONE address serialized at the LLC. Fixes:
//    (1) split-K: wave w owns a K-slice of ALL 4 gates -> A read once per CU,
//        used 4x in-register; cross-wave reduce via padded LDS partials.
//    (2) barrier = per-block ticket stores (no RMW) + one coalesced 32-flag
//        poll by wave 0.
//    (3) h2 LLC loads issued before z1's h1-half MFMAs (latency hidden).
//  - h exchange stays at the LLC coherence point (sc0 sc1) - no cache
//    maintenance anywhere (R6's key insight).
// ---------------------------------------------------------------------------

typedef __bf16        v8bf  __attribute__((ext_vector_type(8)));
typedef float         f32x4 __attribute__((ext_vector_type(4)));
typedef unsigned int  u32x4 __attribute__((ext_vector_type(4)));

constexpr int B_ = 128, T_ = 256, D_ = 64, H_ = 512;

// workspace layout (bytes)
constexpr size_t OFF_WP1 = 0;        // packed [k0;r0] bf16 -> 2359296 B
constexpr size_t OFF_WP2 = 2359296;  // packed [k1;r1] bf16 -> 4194304 B
constexpr size_t OFF_WPP = 6553600;  // packed W bf16       ->   65536 B
constexpr size_t OFF_H1G = 6619136;  // h1 exchange bf16       131072 B
constexpr size_t OFF_H2G = 6750208;  // h2 exchange bf16       131072 B
constexpr size_t OFF_FLG = 6881280;  // 8 chains * 64 u32 =      2048 B

__device__ __forceinline__ v8bf ldv(const __hip_bfloat16* p) {
  return *reinterpret_cast<const v8bf*>(p);
}
__device__ __forceinline__ f32x4 MF(v8bf a, v8bf b, f32x4 c) {
  return __builtin_amdgcn_mfma_f32_16x16x32_bf16(a, b, c, 0, 0, 0);
}
__device__ __forceinline__ float sigf(float x) { return 1.0f / (1.0f + __expf(-x)); }
__device__ __forceinline__ float tanhfast(float x) {
  x = fminf(15.0f, fmaxf(-15.0f, x));
  float e = __expf(-2.0f * x);
  return (1.0f - e) / (1.0f + e);
}

// 16-bit store straight to the device coherence point (LLC).
__device__ __forceinline__ void st_llc_u16(void* p, unsigned v) {
  asm volatile("global_store_short %0, %1, off sc0 sc1" :: "v"(p), "v"(v) : "memory");
}
__device__ __forceinline__ void st_flag(unsigned* p, unsigned v) {
  asm volatile("global_store_dword %0, %1, off sc0 sc1" :: "v"(p), "v"(v) : "memory");
}
__device__ __forceinline__ void vm0() {
  asm volatile("s_waitcnt vmcnt(0)" ::: "memory");
}
// issue 64B of LLC loads (bypass L1/L2); land later with vm0()
__device__ __forceinline__ void ld_llc64_issue(const char* g, u32x4& a, u32x4& b,
                                               u32x4& c, u32x4& d) {
  asm volatile(
      "global_load_dwordx4 %0, %4, off sc0 sc1\n\t"
      "global_load_dwordx4 %1, %4, off offset:16 sc0 sc1\n\t"
      "global_load_dwordx4 %2, %4, off offset:32 sc0 sc1\n\t"
      "global_load_dwordx4 %3, %4, off offset:48 sc0 sc1"
      : "=&v"(a), "=&v"(b), "=&v"(c), "=&v"(d)
      : "v"(g)
      : "memory");
}
// poll all 32 flags of a chain (one coalesced 128B line read per iteration)
__device__ __forceinline__ void poll_flags(const unsigned* fbase, int lane,
                                           unsigned tgt) {
  const unsigned* fp = fbase + (lane & 31);
  unsigned f;
  for (;;) {
    asm volatile("global_load_dword %0, %1, off sc0 sc1\n\ts_waitcnt vmcnt(0)"
                 : "=v"(f) : "v"(fp) : "memory");
    if (!__any((int)(f < tgt))) break;
    __builtin_amdgcn_s_sleep(2);
  }
}

// ---------------------------------------------------------------------------
// Pack B-operand fragments (float32 in, bf16 out):
// out[((ct*nkc + kc)*64 + lane)*8 + j] = Wcat[kc*32 + (lane>>4)*8 + j][ct*16 + (lane&15)]
// ---------------------------------------------------------------------------
__global__ __launch_bounds__(256) void pack_weights(
    const float* __restrict__ kp, const float* __restrict__ rp,
    int krows, int ncols, int nkc, int nct, __hip_bfloat16* __restrict__ out) {
  int tid = blockIdx.x * 256 + threadIdx.x;
  int total = nct * nkc * 64;
  if (tid >= total) return;
  int L  = tid & 63;
  int kc = (tid >> 6) % nkc;
  int ct = tid / (64 * nkc);
  int n  = ct * 16 + (L & 15);
  int kb = kc * 32 + (L >> 4) * 8;
  __hip_bfloat16* dst = out + (size_t)tid * 8;
#pragma unroll
  for (int j = 0; j < 8; ++j) {
    int kk = kb + j;
    float v = (kk < krows) ? kp[kk * ncols + n] : rp[(kk - krows) * ncols + n];
    dst[j] = __float2bfloat16(v);
  }
}

// zero the 512 barrier flags (ws re-poisoned to 0xAA before every call)
__global__ __launch_bounds__(256) void init_state(unsigned* __restrict__ flg) {
  int idx = blockIdx.x * 256 + threadIdx.x;
  if (idx < 512) flg[idx] = 0u;
}

// ---------------------------------------------------------------------------
// Persistent recurrence kernel. Block = (rg,cg): 16 batch rows x 16 h-cols.
// 4 waves = 4 K-slices of ALL 4 gates (split-K). 8 chains of 32 blocks.
// z1 chunk sets (18 chunks; 0,1 = cur, 2..17 = h1):
//   w0:{0,2,3,4,5} w1:{1,6,7,8,9} w2:{10..13} w3:{14..17}
// z2 chunks (32; 0..15 = h1_t, 16..31 = h2_{t-1}): wave w owns w*8..w*8+7
// pred chunks (16): wave w owns w*4..w*4+3 for all 4 col-tiles.
// ---------------------------------------------------------------------------
__global__ __launch_bounds__(256, 1) void rnn_persist(
    const float* __restrict__ x,
    const __hip_bfloat16* __restrict__ Wp1,
    const __hip_bfloat16* __restrict__ Wp2,
    const __hip_bfloat16* __restrict__ WpP,
    const float* __restrict__ b0,
    const float* __restrict__ b1,
    const float* __restrict__ biasD,
    __hip_bfloat16* __restrict__ h1g,
    __hip_bfloat16* __restrict__ h2g,
    unsigned* __restrict__ flg,
    float* __restrict__ pred_out,
    float* __restrict__ last_out) {

  // h tiles: 1024B rows, XOR-swizzled (phys_byte = log_byte ^ ((row&7)<<4))
  __shared__ alignas(16) __hip_bfloat16 h1P[16][512];
  __shared__ alignas(16) __hip_bfloat16 h1Q[16][512];
  __shared__ alignas(16) __hip_bfloat16 h2L[16][512];
  __shared__ alignas(16) __hip_bfloat16 curL[16][72];
  __shared__ alignas(16) float predb[4][16][68];   // per-wave pred partials
  __shared__ float zbp[4][4][16][18];              // [wave][gate][row][col+pad]

  const int tid = threadIdx.x;
  const int rg = blockIdx.x & 7;     // chain id (likely-XCD-local; perf only)
  const int cg = blockIdx.x >> 3;
  const int w  = tid >> 6;
  const int L  = tid & 63;
  const int m  = L & 15;
  const int q  = L >> 4;
  const int row2 = tid >> 4;
  const int col2 = tid & 15;
  const int C  = cg * 16 + col2;
  const int R  = rg * 16 + row2;
  const int c0 = col2 * 4;
  const int sw = (m & 7) << 3;       // element-unit LDS read swizzle for row m

  // stage slot (64B per thread)
  const int srow = row2;
  const int so0  = col2 * 64;
  const int ssw  = (srow & 7) << 4;
  const size_t gso = (size_t)srow * 1024 + so0;

  // ---- weight fragments into registers (split-K layout), once ----
  v8bf wpp[4][4], wp1[4][5], wp2[4][8];
  {
#pragma unroll
    for (int ct = 0; ct < 4; ++ct)
#pragma unroll
      for (int k2 = 0; k2 < 4; ++k2)
        wpp[ct][k2] = ldv(WpP + ((size_t)(ct * 16 + (w * 4 + k2)) * 64 + L) * 8);
#pragma unroll
    for (int g = 0; g < 4; ++g) {
      const size_t ctg1 = (size_t)(g * 32 + cg) * 18;
      const size_t ctg2 = (size_t)(g * 32 + cg) * 32;
      if (w < 2) {
        wp1[g][0] = ldv(Wp1 + ((ctg1 + w) * 64 + L) * 8);
#pragma unroll
        for (int i = 1; i <= 4; ++i)
          wp1[g][i] = ldv(Wp1 + ((ctg1 + (w == 0 ? 1 + i : 5 + i)) * 64 + L) * 8);
      } else {
#pragma unroll
        for (int i = 0; i < 4; ++i)
          wp1[g][i] = ldv(Wp1 + ((ctg1 + 10 + (w - 2) * 4 + i) * 64 + L) * 8);
      }
#pragma unroll
      for (int k2 = 0; k2 < 8; ++k2)
        wp2[g][k2] = ldv(Wp2 + ((ctg2 + (w * 8 + k2)) * 64 + L) * 8);
    }
  }
  const float b0i = b0[C], b0f = b0[512 + C], b0g = b0[1024 + C], b0o = b0[1536 + C];
  const float b1i = b1[C], b1f = b1[512 + C], b1g = b1[1024 + C], b1o = b1[1536 + C];
  const float4 bD4 = *reinterpret_cast<const float4*>(biasD + c0);

  float c1v = 0.0f, c2v = 0.0f;      // cell state in registers

  const size_t rgbase = (size_t)rg * 16 * H_;
  const float* xrow = x + (size_t)R * T_ * D_;
  float* prow = pred_out + (size_t)R * (T_ - 1) * D_;
  unsigned* fbase = flg + (rg << 6);
  const int hidx = R * H_ + C;

  // prologue: h1(-1) = 0, h2(-1) = 0 directly in LDS (no global stage)
  {
    u32x4 zz = {0u, 0u, 0u, 0u};
    u32x4* p1 = reinterpret_cast<u32x4*>(&h1P[0][0]);
    u32x4* p2 = reinterpret_cast<u32x4*>(&h2L[0][0]);
#pragma unroll
    for (int i = 0; i < 4; ++i) { p1[tid * 4 + i] = zz; p2[tid * 4 + i] = zz; }
  }

  for (int t = 0; t < T_; ++t) {
    __hip_bfloat16 (*h1L)[512] = (t & 1) ? h1Q : h1P;  // h1_{t-1}
    __hip_bfloat16 (*h1N)[512] = (t & 1) ? h1P : h1Q;  // h1_t

    const float4 xv = *reinterpret_cast<const float4*>(xrow + t * D_ + c0);

    // ---- P0: wait barrier-2(t-1): h2(t-1) visible at LLC ----
    if (t > 0 && w == 0) poll_flags(fbase, L, 2u * (unsigned)t);
    __syncthreads();

    // ---- P1: issue h2(t-1) LLC loads (latency hidden under P2) ----
    u32x4 sa, sb, sc2, sd;
    if (t > 0)
      ld_llc64_issue((const char*)(h2g + rgbase) + gso, sa, sb, sc2, sd);

    // ---- P2: z1 h1-part (split-K, 4 chunks x 4 gates per wave) ----
    f32x4 z1a[4] = {{0.f,0.f,0.f,0.f},{0.f,0.f,0.f,0.f},{0.f,0.f,0.f,0.f},{0.f,0.f,0.f,0.f}};
    if (w < 2) {
#pragma unroll
      for (int i = 1; i <= 4; ++i) {
        const int c = (w == 0 ? 1 + i : 5 + i) - 2;   // h1 chunk 0..7
        v8bf a = ldv(&h1L[m][(c * 32 + q * 8) ^ sw]);
#pragma unroll
        for (int g = 0; g < 4; ++g) z1a[g] = MF(a, wp1[g][i], z1a[g]);
      }
    } else {
#pragma unroll
      for (int i = 0; i < 4; ++i) {
        const int c = 8 + (w - 2) * 4 + i;            // h1 chunk 8..15
        v8bf a = ldv(&h1L[m][(c * 32 + q * 8) ^ sw]);
#pragma unroll
        for (int g = 0; g < 4; ++g) z1a[g] = MF(a, wp1[g][i], z1a[g]);
      }
    }

    // ---- P3: land h2 into LDS ----
    if (t > 0) {
      vm0();
      char* lb = (char*)(&h2L[srow][0]);
      *(u32x4*)(lb + ((so0 +  0) ^ ssw)) = sa;
      *(u32x4*)(lb + ((so0 + 16) ^ ssw)) = sb;
      *(u32x4*)(lb + ((so0 + 32) ^ ssw)) = sc2;
      *(u32x4*)(lb + ((so0 + 48) ^ ssw)) = sd;
    }
    __syncthreads();

    // ---- P4: pred partials (split-K: 4 chunks x 4 col-tiles per wave) ----
    if (t > 0) {
      f32x4 pa[4] = {{0.f,0.f,0.f,0.f},{0.f,0.f,0.f,0.f},{0.f,0.f,0.f,0.f},{0.f,0.f,0.f,0.f}};
      v8bf A[4];
#pragma unroll
      for (int k2 = 0; k2 < 4; ++k2)
        A[k2] = ldv(&h2L[m][((w * 4 + k2) * 32 + q * 8) ^ sw]);
#pragma unroll
      for (int ct = 0; ct < 4; ++ct)
#pragma unroll
        for (int k2 = 0; k2 < 4; ++k2)
          pa[ct] = MF(A[k2], wpp[ct][k2], pa[ct]);
#pragma unroll
      for (int ct = 0; ct < 4; ++ct)
#pragma unroll
        for (int r = 0; r < 4; ++r)
          predb[w][q * 4 + r][ct * 16 + m] = pa[ct][r];
    }
    __syncthreads();

    // ---- P5: pred reduce + cur build; cg==0 streams pred -> d_out ----
    {
      float4 pv = {0.f, 0.f, 0.f, 0.f};
      if (t > 0) {
#pragma unroll
        for (int wv = 0; wv < 4; ++wv) {
          const float4 p = *reinterpret_cast<const float4*>(&predb[wv][row2][c0]);
          pv.x += p.x; pv.y += p.y; pv.z += p.z; pv.w += p.w;
        }
        pv.x += bD4.x; pv.y += bD4.y; pv.z += bD4.z; pv.w += bD4.w;
      }
      const float xa[4] = {xv.x, xv.y, xv.z, xv.w};
      const float pp[4] = {pv.x, pv.y, pv.z, pv.w};
#pragma unroll
      for (int j = 0; j < 4; ++j) {
        const bool missv = (t > 0) && (xa[j] == 128.0f);
        curL[row2][c0 + j] = __float2bfloat16(missv ? pp[j] : xa[j]);
      }
      if (cg == 0 && t > 0)
        *reinterpret_cast<float4*>(prow + (size_t)(t - 1) * D_ + c0) = pv;
    }
    __syncthreads();

    // ---- P6: z1 cur-part (waves 0,1) + write z1 partials ----
    if (w < 2) {
      v8bf a = ldv(&curL[m][w * 32 + q * 8]);
#pragma unroll
      for (int g = 0; g < 4; ++g) z1a[g] = MF(a, wp1[g][0], z1a[g]);
    }
#pragma unroll
    for (int g = 0; g < 4; ++g)
#pragma unroll
      for (int r = 0; r < 4; ++r)
        zbp[w][g][q * 4 + r][m] = z1a[g][r];
    __syncthreads();

    // ---- P7: z1 reduce, L1 gates, h1_t -> LLC, signal barrier-1 ----
    {
      float zi = 0.f, zf = 0.f, zg = 0.f, zo = 0.f;
#pragma unroll
      for (int wv = 0; wv < 4; ++wv) {
        zi += zbp[wv][0][row2][col2];
        zf += zbp[wv][1][row2][col2];
        zg += zbp[wv][2][row2][col2];
        zo += zbp[wv][3][row2][col2];
      }
      float ig = sigf(zi + b0i), fg = sigf(zf + b0f);
      float gg = tanhfast(zg + b0g), og = sigf(zo + b0o);
      c1v = fg * c1v + ig * gg;
      float hn = og * tanhfast(c1v);
      st_llc_u16(&h1g[hidx], (unsigned)__builtin_bit_cast(unsigned short,
                                                          __float2bfloat16(hn)));
    }
    vm0();
    __syncthreads();
    if (tid == 0) st_flag(fbase + cg, 2u * (unsigned)t + 1u);

    // ---- P8: z2 h2-half (waves 2,3) overlaps barrier-1 poll (wave 0) ----
    f32x4 z2a[4] = {{0.f,0.f,0.f,0.f},{0.f,0.f,0.f,0.f},{0.f,0.f,0.f,0.f},{0.f,0.f,0.f,0.f}};
    if (w >= 2) {
#pragma unroll
      for (int k2 = 0; k2 < 8; ++k2) {
        const int c = (w - 2) * 8 + k2;               // h2 chunk 0..15
        v8bf a = ldv(&h2L[m][(c * 32 + q * 8) ^ sw]);
#pragma unroll
        for (int g = 0; g < 4; ++g) z2a[g] = MF(a, wp2[g][k2], z2a[g]);
      }
    } else if (w == 0) {
      poll_flags(fbase, L, 2u * (unsigned)t + 1u);
    }
    __syncthreads();

    // ---- P9: stage h1_t -> h1N ----
    ld_llc64_issue((const char*)(h1g + rgbase) + gso, sa, sb, sc2, sd);
    vm0();
    {
      char* lb = (char*)(&h1N[srow][0]);
      *(u32x4*)(lb + ((so0 +  0) ^ ssw)) = sa;
      *(u32x4*)(lb + ((so0 + 16) ^ ssw)) = sb;
      *(u32x4*)(lb + ((so0 + 32) ^ ssw)) = sc2;
      *(u32x4*)(lb + ((so0 + 48) ^ ssw)) = sd;
    }
    __syncthreads();

    // ---- P10: z2 h1-half (waves 0,1) + write z2 partials ----
    if (w < 2) {
#pragma unroll
      for (int k2 = 0; k2 < 8; ++k2) {
        const int c = w * 8 + k2;                     // h1 chunk 0..15
        v8bf a = ldv(&h1N[m][(c * 32 + q * 8) ^ sw]);
#pragma unroll
        for (int g = 0; g < 4; ++g) z2a[g] = MF(a, wp2[g][k2], z2a[g]);
      }
    }
#pragma unroll
    for (int g = 0; g < 4; ++g)
#pragma unroll
      for (int r = 0; r < 4; ++r)
        zbp[w][g][q * 4 + r][m] = z2a[g][r];
    __syncthreads();

    // ---- P11: z2 reduce, L2 gates, h2_t -> LLC (or last_cell) ----
    {
      float zi = 0.f, zf = 0.f, zg = 0.f, zo = 0.f;
#pragma unroll
      for (int wv = 0; wv < 4; ++wv) {
        zi += zbp[wv][0][row2][col2];
        zf += zbp[wv][1][row2][col2];
        zg += zbp[wv][2][row2][col2];
        zo += zbp[wv][3][row2][col2];
      }
      float ig = sigf(zi + b1i), fg = sigf(zf + b1f);
      float gg = tanhfast(zg + b1g), og = sigf(zo + b1o);
      c2v = fg * c2v + ig * gg;
      float hn = og * tanhfast(c2v);
      if (t == T_ - 1) {
        last_out[hidx] = hn;
      } else {
        st_llc_u16(&h2g[hidx], (unsigned)__builtin_bit_cast(unsigned short,
                                                            __float2bfloat16(hn)));
        vm0();
      }
    }
    if (t == T_ - 1) break;
    __syncthreads();
    if (tid == 0) st_flag(fbase + cg, 2u * (unsigned)t + 2u);
  }
}

// ---------------------------------------------------------------------------
extern "C" void kernel_launch(void* const* d_in, const int* in_sizes, int n_in,
                              void* d_out, int out_size, void* d_ws, size_t ws_size,
                              hipStream_t stream) {
  const float* x    = (const float*)d_in[0];
  const float* k0   = (const float*)d_in[1];
  const float* r0   = (const float*)d_in[2];
  const float* b0   = (const float*)d_in[3];
  const float* k1   = (const float*)d_in[4];
  const float* r1   = (const float*)d_in[5];
  const float* b1   = (const float*)d_in[6];
  const float* W    = (const float*)d_in[7];
  const float* bias = (const float*)d_in[8];

  char* ws = (char*)d_ws;
  __hip_bfloat16* Wp1 = (__hip_bfloat16*)(ws + OFF_WP1);
  __hip_bfloat16* Wp2 = (__hip_bfloat16*)(ws + OFF_WP2);
  __hip_bfloat16* WpP = (__hip_bfloat16*)(ws + OFF_WPP);
  __hip_bfloat16* h1g = (__hip_bfloat16*)(ws + OFF_H1G);
  __hip_bfloat16* h2g = (__hip_bfloat16*)(ws + OFF_H2G);
  unsigned*       flg = (unsigned*)(ws + OFF_FLG);

  pack_weights<<<(128 * 18 * 64 + 255) / 256, 256, 0, stream>>>(k0, r0, 64, 2048, 18, 128, Wp1);
  pack_weights<<<(128 * 32 * 64 + 255) / 256, 256, 0, stream>>>(k1, r1, 512, 2048, 32, 128, Wp2);
  pack_weights<<<(4 * 16 * 64 + 255) / 256, 256, 0, stream>>>(W, W, 512, 64, 16, 4, WpP);
  init_state<<<2, 256, 0, stream>>>(flg);

  float* outp = (float*)d_out;
  float* last = outp + (size_t)B_ * (T_ - 1) * D_;

  rnn_persist<<<256, 256, 0, stream>>>(x, Wp1, Wp2, WpP, b0, b1, bias,
                                       h1g, h2g, flg, outp, last);
}